// Round 15
// baseline (425.929 us; speedup 1.0000x reference)
//
#include <hip/hip_runtime.h>
#include <math.h>

#define N_NODES 100000
#define N_EDGES 1600000
#define DIM     128
#define NCLS    40
#define NBUCK   196      // ceil(100000/512) buckets of 512 nodes
#define P1_CH   4096     // edges per phase-1 block
#define P1_GRID 391      // ceil(1600000/4096)

typedef _Float16 f16x8 __attribute__((ext_vector_type(8)));
typedef _Float16 f16x2 __attribute__((ext_vector_type(2)));
typedef float    f32x4 __attribute__((ext_vector_type(4)));

__device__ inline unsigned short f16bits(float f) {
    union { _Float16 h; unsigned short u; } cv;
    cv.h = (_Float16)f;
    return cv.u;
}
__device__ inline f16x2 as_h2(unsigned u) {
    union { unsigned u; f16x2 h; } cv;
    cv.u = u;
    return cv.h;
}
__device__ inline unsigned as_u(f16x2 h) {
    union { f16x2 h; unsigned u; } cv;
    cv.h = h;
    return cv.u;
}
__device__ inline unsigned pack_h2(float lo, float hi) {
    f16x2 h;
    h.x = (_Float16)lo;
    h.y = (_Float16)hi;
    return as_u(h);
}

// ---------------------------------------------------------------- setup: W swizzles + bucket histogram (bcnt pre-zeroed)
// blocks 0..191: Wsw0/1/2; 192..215: Wcsw; 216..606: bhist
__global__ __launch_bounds__(256) void setup_misc(const float* __restrict__ W0,
                                                  const float* __restrict__ W1,
                                                  const float* __restrict__ W2,
                                                  const float* __restrict__ Wc,
                                                  const int* __restrict__ ei,
                                                  unsigned short* __restrict__ Wsw0,
                                                  unsigned short* __restrict__ Wsw1,
                                                  unsigned short* __restrict__ Wsw2,
                                                  unsigned short* __restrict__ Wcsw,
                                                  int* __restrict__ bcnt) {
    int blk = blockIdx.x;
    if (blk < 192) {
        const float* W = (blk < 64) ? W0 : (blk < 128) ? W1 : W2;
        unsigned short* Wsw = (blk < 64) ? Wsw0 : (blk < 128) ? Wsw1 : Wsw2;
        int o = (blk & 63) * 256 + threadIdx.x;  // 0..16383
        int f = o >> 9;
        int l = (o >> 3) & 63;
        int j = o & 7;
        int n = f >> 2;
        int s = f & 3;
        int k = s * 32 + (l >> 4) * 8 + j;
        int c = (l & 15) * 8 + n;
        Wsw[o] = f16bits(W[k * DIM + c]);
    } else if (blk < 216) {
        int o = (blk - 192) * 256 + threadIdx.x; // 0..6143
        int f = o >> 9;
        int l = (o >> 3) & 63;
        int j = o & 7;
        int n = f >> 2;
        int s = f & 3;
        int k = s * 32 + (l >> 4) * 8 + j;
        int c = (l & 15) * 3 + n;
        Wcsw[o] = (c < NCLS) ? f16bits(Wc[k * NCLS + c]) : (unsigned short)0;
    } else {
        __shared__ int h[256];
        const int t  = threadIdx.x;
        const int e0 = (blk - 216) * P1_CH;
        const int cnt = min(P1_CH, N_EDGES - e0);
        h[t] = 0;
        __syncthreads();
        for (int i = t; i < cnt; i += 256)
            atomicAdd(&h[ei[N_EDGES + e0 + i] >> 9], 1);
        __syncthreads();
        if (h[t]) atomicAdd(&bcnt[t], h[t]);
    }
}

// ---------------------------------------------------------------- bucket scan (1 block): bbase (exclusive), bcur = bbase
__global__ __launch_bounds__(256) void bscan(const int* __restrict__ bcnt,
                                             int* __restrict__ bbase,
                                             int* __restrict__ bcur) {
    __shared__ int s[256];
    int t = threadIdx.x;
    s[t] = (t < NBUCK) ? bcnt[t] : 0;
    __syncthreads();
    for (int off = 1; off < 256; off <<= 1) {
        int x = (t >= off) ? s[t - off] : 0;
        __syncthreads();
        s[t] += x;
        __syncthreads();
    }
    int excl = (t == 0) ? 0 : s[t - 1];
    if (t < NBUCK) {
        bbase[t] = excl;
        bcur[t]  = excl;
    }
    if (t == 0) bbase[NBUCK] = N_EDGES;
}

// ---------------------------------------------------------------- phase 1: bucket edges by dst>>9 into tmp (coalesced runs)
__global__ __launch_bounds__(256) void bucket_p1(const int* __restrict__ ei,
                                                 int* __restrict__ bcur,
                                                 int2* __restrict__ tmp) {
    __shared__ int  hist[256];
    __shared__ int  lscan[256];
    __shared__ int  rank[256];
    __shared__ int  gbase[256];
    __shared__ int2 stage[P1_CH];      // 32 KB
    const int t  = threadIdx.x;
    const int e0 = blockIdx.x * P1_CH;
    const int cnt = min(P1_CH, N_EDGES - e0);

    hist[t] = 0;
    __syncthreads();

    int2 ed[16];
#pragma unroll
    for (int i = 0; i < 16; ++i) {
        int idx = t + i * 256;
        if (idx < cnt) {
            int s = ei[e0 + idx];
            int d = ei[N_EDGES + e0 + idx];
            ed[i] = make_int2(s, d);
            atomicAdd(&hist[d >> 9], 1);
        }
    }
    __syncthreads();

    int hv = hist[t];
    lscan[t] = hv;
    __syncthreads();
    for (int off = 1; off < 256; off <<= 1) {
        int x = (t >= off) ? lscan[t - off] : 0;
        __syncthreads();
        lscan[t] += x;
        __syncthreads();
    }
    int excl = (t == 0) ? 0 : lscan[t - 1];
    __syncthreads();
    lscan[t] = excl;
    rank[t]  = excl;
    if (hv > 0) gbase[t] = atomicAdd(&bcur[t], hv);
    __syncthreads();

#pragma unroll
    for (int i = 0; i < 16; ++i) {
        int idx = t + i * 256;
        if (idx < cnt) {
            int b = ed[i].y >> 9;
            int p = atomicAdd(&rank[b], 1);
            stage[p] = ed[i];
        }
    }
    __syncthreads();

    for (int p = t; p < cnt; p += 256) {
        int2 v = stage[p];
        int b = v.y >> 9;
        tmp[gbase[b] + (p - lscan[b])] = v;
    }
}

// ---------------------------------------------------------------- phase 2a: per-bucket node counts (LDS) -> rowptr + dinv
__global__ __launch_bounds__(256) void bucket_p2a(const int2* __restrict__ tmp,
                                                  const int* __restrict__ bbase,
                                                  int* __restrict__ rowptr,
                                                  float* __restrict__ dinv) {
    __shared__ int cnt[512];
    __shared__ int pscan[256];
    const int t  = threadIdx.x;
    const int b  = blockIdx.x;
    const int d0 = b << 9;
    const int dend = min(d0 + 512, N_NODES);
    const int nn = dend - d0;

    cnt[t] = 0;
    cnt[t + 256] = 0;
    __syncthreads();

    const int beg = bbase[b];
    const int end = bbase[b + 1];
    for (int idx = beg + t; idx < end; idx += 256)
        atomicAdd(&cnt[tmp[idx].y - d0], 1);
    __syncthreads();

    int c0 = cnt[2 * t];
    int c1 = cnt[2 * t + 1];
    pscan[t] = c0 + c1;
    __syncthreads();
    for (int off = 1; off < 256; off <<= 1) {
        int x = (t >= off) ? pscan[t - off] : 0;
        __syncthreads();
        pscan[t] += x;
        __syncthreads();
    }
    int excl = (t == 0) ? 0 : pscan[t - 1];
    if (2 * t < nn) {
        rowptr[d0 + 2 * t] = beg + excl;
        dinv[d0 + 2 * t]   = rsqrtf((float)c0 + 1.0f);
    }
    if (2 * t + 1 < nn) {
        rowptr[d0 + 2 * t + 1] = beg + excl + c0;
        dinv[d0 + 2 * t + 1]   = rsqrtf((float)c1 + 1.0f);
    }
    if (b == NBUCK - 1 && t == 0) rowptr[N_NODES] = N_EDGES;
}

// ---------------------------------------------------------------- phase 2b: within-bucket scatter; rec = (src*256, half2(w,w))
__global__ __launch_bounds__(256) void bucket_p2b(const int2* __restrict__ tmp,
                                                  const int* __restrict__ rowptr,
                                                  const float* __restrict__ dinv,
                                                  int2* __restrict__ rec) {
    __shared__ int cur[512];
    const int t  = threadIdx.x;
    const int b  = blockIdx.x;
    const int d0 = b << 9;
    const int dend = min(d0 + 512, N_NODES);
    const int nn = dend - d0;

    for (int i = t; i < nn; i += 256) cur[i] = rowptr[d0 + i];
    __syncthreads();

    const int beg = rowptr[d0];
    const int end = rowptr[dend];
    for (int idx = beg + t; idx < end; idx += 256) {
        int2 v = tmp[idx];
        int s = v.x, d = v.y;
        int pos = atomicAdd(&cur[d - d0], 1);
        unsigned short wb = f16bits(dinv[s] * dinv[d]);
        rec[pos] = make_int2(s << 8, (int)((unsigned)wb | ((unsigned)wb << 16)));
    }
}

// ---------------------------------------------------------------- MFMA GEMM, fp32 input (layer 0): 16 rows/wave, W frags from LDS
__global__ __launch_bounds__(256) void gemm_mfma_f(const float* __restrict__ X,
                                                   const unsigned short* __restrict__ Wsw,
                                                   unsigned short* __restrict__ H) {
    __shared__ unsigned short wlds[32 * 512];   // 32 KB
    const int tid   = threadIdx.x;
    const int lane  = tid & 63;
    const int wave  = tid >> 6;
    const int row0w = blockIdx.x * 64 + wave * 16;
    const int m = lane & 15;
    const int q = lane >> 4;

    {
        const uint4* srcp = (const uint4*)Wsw;
        uint4*       dstp = (uint4*)wlds;
#pragma unroll
        for (int i = 0; i < 8; ++i) dstp[tid + i * 256] = srcp[tid + i * 256];
    }
    __syncthreads();

    int r = row0w + m;
    if (r >= N_NODES) r = N_NODES - 1;
    const float* xp = X + (size_t)r * DIM + q * 8;
    f16x8 af[4];
#pragma unroll
    for (int s = 0; s < 4; ++s) {
        float4 x0 = *(const float4*)(xp + s * 32);
        float4 x1 = *(const float4*)(xp + s * 32 + 4);
        f16x8 v;
        v[0] = (_Float16)x0.x; v[1] = (_Float16)x0.y;
        v[2] = (_Float16)x0.z; v[3] = (_Float16)x0.w;
        v[4] = (_Float16)x1.x; v[5] = (_Float16)x1.y;
        v[6] = (_Float16)x1.z; v[7] = (_Float16)x1.w;
        af[s] = v;
    }

    f32x4 acc[8];
    f32x4 z = {0.f, 0.f, 0.f, 0.f};
#pragma unroll
    for (int n = 0; n < 8; ++n) acc[n] = z;

    const unsigned short* wl = wlds + lane * 8;
#pragma unroll
    for (int s = 0; s < 4; ++s)
#pragma unroll
        for (int n = 0; n < 8; ++n) {
            f16x8 wf = *(const f16x8*)(wl + ((n * 4 + s) << 9));
            acc[n] = __builtin_amdgcn_mfma_f32_16x16x32_f16(af[s], wf, acc[n], 0, 0, 0);
        }

#pragma unroll
    for (int j = 0; j < 4; ++j) {
        int row = row0w + q * 4 + j;
        if (row < N_NODES) {
            uint4 o;
            o.x = pack_h2(acc[0][j], acc[1][j]);
            o.y = pack_h2(acc[2][j], acc[3][j]);
            o.z = pack_h2(acc[4][j], acc[5][j]);
            o.w = pack_h2(acc[6][j], acc[7][j]);
            *(uint4*)(H + (size_t)row * DIM + m * 8) = o;
        }
    }
}

// ---------------------------------------------------------------- MFMA GEMM, f16 input (layers 1,2): 16 rows/wave, W frags from LDS
__global__ __launch_bounds__(256) void gemm_mfma_h(const unsigned short* __restrict__ Xh,
                                                   const unsigned short* __restrict__ Wsw,
                                                   unsigned short* __restrict__ H) {
    __shared__ unsigned short wlds[32 * 512];   // 32 KB
    const int tid   = threadIdx.x;
    const int lane  = tid & 63;
    const int wave  = tid >> 6;
    const int row0w = blockIdx.x * 64 + wave * 16;
    const int m = lane & 15;
    const int q = lane >> 4;

    {
        const uint4* srcp = (const uint4*)Wsw;
        uint4*       dstp = (uint4*)wlds;
#pragma unroll
        for (int i = 0; i < 8; ++i) dstp[tid + i * 256] = srcp[tid + i * 256];
    }
    __syncthreads();

    int r = row0w + m;
    if (r >= N_NODES) r = N_NODES - 1;
    const unsigned short* xp = Xh + (size_t)r * DIM + q * 8;
    f16x8 af[4];
#pragma unroll
    for (int s = 0; s < 4; ++s) af[s] = *(const f16x8*)(xp + s * 32);

    f32x4 acc[8];
    f32x4 z = {0.f, 0.f, 0.f, 0.f};
#pragma unroll
    for (int n = 0; n < 8; ++n) acc[n] = z;

    const unsigned short* wl = wlds + lane * 8;
#pragma unroll
    for (int s = 0; s < 4; ++s)
#pragma unroll
        for (int n = 0; n < 8; ++n) {
            f16x8 wf = *(const f16x8*)(wl + ((n * 4 + s) << 9));
            acc[n] = __builtin_amdgcn_mfma_f32_16x16x32_f16(af[s], wf, acc[n], 0, 0, 0);
        }

#pragma unroll
    for (int j = 0; j < 4; ++j) {
        int row = row0w + q * 4 + j;
        if (row < N_NODES) {
            uint4 o;
            o.x = pack_h2(acc[0][j], acc[1][j]);
            o.y = pack_h2(acc[2][j], acc[3][j]);
            o.z = pack_h2(acc[4][j], acc[5][j]);
            o.w = pack_h2(acc[6][j], acc[7][j]);
            *(uint4*)(H + (size_t)row * DIM + m * 8) = o;
        }
    }
}

// ---------------------------------------------------------------- fused gather-aggregate + LN + ELU (+ residual), f16
__global__ __launch_bounds__(256) void agg_ln(const unsigned short* __restrict__ Hh,
                                              const unsigned short* __restrict__ xin,
                                              const float* __restrict__ dinv,
                                              const float* __restrict__ bias,
                                              const float* __restrict__ g,
                                              const float* __restrict__ be,
                                              const int* __restrict__ rowptr,
                                              const int2* __restrict__ rec,
                                              unsigned short* __restrict__ outb) {
    int node = blockIdx.x * 4 + (threadIdx.x >> 6);
    int lane = threadIdx.x & 63;
    int sub  = lane & 15;
    int qtr  = lane >> 4;
    int beg = rowptr[node];
    int end = rowptr[node + 1];
    const char* Hb8 = (const char*)Hh;
    const unsigned laneoff = (unsigned)sub * 16;   // byte offset within row

    f16x2 acc[4];
    f16x2 hz = {(_Float16)0.f, (_Float16)0.f};
#pragma unroll
    for (int k = 0; k < 4; ++k) acc[k] = hz;

    for (int e0 = beg; e0 < end; e0 += 64) {
        int cnt = min(end - e0, 64);
        int2 rc = (lane < cnt) ? rec[e0 + lane] : make_int2(0, 0);
        int sv = rc.x;                        // src*256 byte offset (pads have w=0)
        int wv = rc.y;                        // packed half2 (w,w)
        int cntR = (cnt + 15) & ~15;
        for (int j = 0; j < cntR; j += 16) {
            int i0 = j + qtr, i1 = j + 4 + qtr, i2 = j + 8 + qtr, i3 = j + 12 + qtr;
            unsigned o0 = (unsigned)__shfl(sv, i0, 64) + laneoff;
            int      w0 = __shfl(wv, i0, 64);
            unsigned o1 = (unsigned)__shfl(sv, i1, 64) + laneoff;
            int      w1 = __shfl(wv, i1, 64);
            unsigned o2 = (unsigned)__shfl(sv, i2, 64) + laneoff;
            int      w2 = __shfl(wv, i2, 64);
            unsigned o3 = (unsigned)__shfl(sv, i3, 64) + laneoff;
            int      w3 = __shfl(wv, i3, 64);
            uint4 u0 = *(const uint4*)(Hb8 + o0);
            uint4 u1 = *(const uint4*)(Hb8 + o1);
            uint4 u2 = *(const uint4*)(Hb8 + o2);
            uint4 u3 = *(const uint4*)(Hb8 + o3);
            f16x2 hw0 = as_h2(w0), hw1 = as_h2(w1), hw2 = as_h2(w2), hw3 = as_h2(w3);
            acc[0] += as_h2(u0.x) * hw0;
            acc[1] += as_h2(u0.y) * hw0;
            acc[2] += as_h2(u0.z) * hw0;
            acc[3] += as_h2(u0.w) * hw0;
            acc[0] += as_h2(u1.x) * hw1;
            acc[1] += as_h2(u1.y) * hw1;
            acc[2] += as_h2(u1.z) * hw1;
            acc[3] += as_h2(u1.w) * hw1;
            acc[0] += as_h2(u2.x) * hw2;
            acc[1] += as_h2(u2.y) * hw2;
            acc[2] += as_h2(u2.z) * hw2;
            acc[3] += as_h2(u2.w) * hw2;
            acc[0] += as_h2(u3.x) * hw3;
            acc[1] += as_h2(u3.y) * hw3;
            acc[2] += as_h2(u3.z) * hw3;
            acc[3] += as_h2(u3.w) * hw3;
        }
    }

#pragma unroll
    for (int k = 0; k < 4; ++k) {
        acc[k] += as_h2(__shfl_xor(as_u(acc[k]), 16, 64));
        acc[k] += as_h2(__shfl_xor(as_u(acc[k]), 32, 64));
    }

    unsigned mu = as_u(acc[0]);
    mu = (qtr == 1) ? as_u(acc[1]) : mu;
    mu = (qtr == 2) ? as_u(acc[2]) : mu;
    mu = (qtr == 3) ? as_u(acc[3]) : mu;
    f16x2 mine = as_h2(mu);
    const int c0 = sub * 8 + qtr * 2;
    const unsigned nodeoff = ((unsigned)node << 8) + (unsigned)c0 * 2;

    float dv = dinv[node];
    float d2 = dv * dv;
    f16x2 hh = as_h2(*(const unsigned*)(Hb8 + nodeoff));
    float2 bb = *(const float2*)(bias + c0);
    float a0 = (float)mine.x + (float)hh.x * d2 + bb.x;
    float a1 = (float)mine.y + (float)hh.y * d2 + bb.y;

    float s1 = a0 + a1;
    float s2 = a0 * a0 + a1 * a1;
#pragma unroll
    for (int mk = 1; mk <= 32; mk <<= 1) {
        s1 += __shfl_xor(s1, mk, 64);
        s2 += __shfl_xor(s2, mk, 64);
    }
    float mean = s1 * (1.0f / 128.0f);
    float var  = s2 * (1.0f / 128.0f) - mean * mean;
    float rr   = rsqrtf(var + 1e-5f);
    float2 gg = *(const float2*)(g + c0);
    float2 ee = *(const float2*)(be + c0);
    float r0 = (a0 - mean) * rr * gg.x + ee.x;
    float r1 = (a1 - mean) * rr * gg.y + ee.y;
    r0 = r0 > 0.0f ? r0 : expm1f(r0);
    r1 = r1 > 0.0f ? r1 : expm1f(r1);
    if (xin) {
        f16x2 xi = as_h2(*(const unsigned*)((const char*)xin + nodeoff));
        r0 += (float)xi.x;
        r1 += (float)xi.y;
    }
    *(unsigned*)((char*)outb + nodeoff) = pack_h2(r0, r1);
}

// ---------------------------------------------------------------- MFMA classifier, f16 input: 32 rows/wave, Wc via LDS
__global__ __launch_bounds__(256) void classifier_mfma(const unsigned short* __restrict__ Xh,
                                                       const unsigned short* __restrict__ Wcsw,
                                                       const float* __restrict__ bc,
                                                       float* __restrict__ out) {
    __shared__ unsigned short wlds[12 * 512];   // 12 KB
    const int tid   = threadIdx.x;
    const int lane  = tid & 63;
    const int wave  = tid >> 6;
    const int row0w = blockIdx.x * 128 + wave * 32;
    const int m = lane & 15;
    const int q = lane >> 4;

    {
        const uint4* srcp = (const uint4*)Wcsw;
        uint4*       dstp = (uint4*)wlds;
#pragma unroll
        for (int i = 0; i < 3; ++i) dstp[tid + i * 256] = srcp[tid + i * 256];
    }
    __syncthreads();

    f16x8 wf[12];
#pragma unroll
    for (int f = 0; f < 12; ++f)
        wf[f] = *(const f16x8*)(wlds + (f << 9) + lane * 8);

    f16x8 af[2][4];
#pragma unroll
    for (int ggr = 0; ggr < 2; ++ggr) {
        int r = row0w + ggr * 16 + m;
        if (r >= N_NODES) r = N_NODES - 1;
        const unsigned short* xp = Xh + (size_t)r * DIM + q * 8;
#pragma unroll
        for (int s = 0; s < 4; ++s) af[ggr][s] = *(const f16x8*)(xp + s * 32);
    }

    f32x4 acc[2][3];
    f32x4 z = {0.f, 0.f, 0.f, 0.f};
#pragma unroll
    for (int ggr = 0; ggr < 2; ++ggr)
#pragma unroll
        for (int n = 0; n < 3; ++n) acc[ggr][n] = z;

#pragma unroll
    for (int s = 0; s < 4; ++s)
#pragma unroll
        for (int n = 0; n < 3; ++n) {
            acc[0][n] = __builtin_amdgcn_mfma_f32_16x16x32_f16(af[0][s], wf[n * 4 + s], acc[0][n], 0, 0, 0);
            acc[1][n] = __builtin_amdgcn_mfma_f32_16x16x32_f16(af[1][s], wf[n * 4 + s], acc[1][n], 0, 0, 0);
        }

    float bcv[3];
#pragma unroll
    for (int n = 0; n < 3; ++n) {
        int c = 3 * m + n;
        bcv[n] = (c < NCLS) ? bc[c] : 0.f;
    }

#pragma unroll
    for (int ggr = 0; ggr < 2; ++ggr)
#pragma unroll
        for (int j = 0; j < 4; ++j) {
            int row = row0w + ggr * 16 + q * 4 + j;
            if (row < N_NODES) {
#pragma unroll
                for (int n = 0; n < 3; ++n) {
                    int c = 3 * m + n;
                    if (c < NCLS)
                        out[(size_t)row * NCLS + c] = acc[ggr][n][j] + bcv[n];
                }
            }
        }
}

// ---------------------------------------------------------------- launch
extern "C" void kernel_launch(void* const* d_in, const int* in_sizes, int n_in,
                              void* d_out, int out_size, void* d_ws, size_t ws_size,
                              hipStream_t stream) {
    const float* x  = (const float*)d_in[0];
    const int*   ei = (const int*)d_in[1];
    const float* W[3]  = {(const float*)d_in[2], (const float*)d_in[6], (const float*)d_in[10]};
    const float* b[3]  = {(const float*)d_in[3], (const float*)d_in[7], (const float*)d_in[11]};
    const float* g[3]  = {(const float*)d_in[4], (const float*)d_in[8], (const float*)d_in[12]};
    const float* be[3] = {(const float*)d_in[5], (const float*)d_in[9], (const float*)d_in[13]};
    const float* Wc = (const float*)d_in[14];
    const float* bc = (const float*)d_in[15];
    float* out = (float*)d_out;

    char* ws = (char*)d_ws;
    const size_t NP = 400128;  // padded (N+1)*4 bytes
    float* dinv   = (float*)(ws);
    int*   rowptr = (int*)  (ws + NP);
    int*   bcnt   = (int*)  (ws + 2 * NP);
    int*   bbase  = (int*)  (ws + 2 * NP + 1024);
    int*   bcur   = (int*)  (ws + 2 * NP + 2048);
    int2*  rec    = (int2*) (ws + 2 * NP + 4096);
    unsigned short* Hh = (unsigned short*)(ws + 2 * NP + 4096 + (size_t)N_EDGES * 8);
    unsigned short* Ah = Hh + (size_t)N_NODES * DIM;
    unsigned short* Ch = Ah + (size_t)N_NODES * DIM;
    unsigned short* Wsw0 = Ch + (size_t)N_NODES * DIM;
    unsigned short* Wsw1 = Wsw0 + DIM * DIM;
    unsigned short* Wsw2 = Wsw1 + DIM * DIM;
    unsigned short* Wcsw = Wsw2 + DIM * DIM;   // 12*512 shorts
    int2*  tmp    = (int2*)Ch;                 // aliases Ch; dead before layer 0 writes Ch

    // ---- setup: zero bcnt (memset) + swizzles + bucket histogram (1 dispatch) ----
    hipMemsetAsync(bcnt, 0, 1024, stream);
    setup_misc<<<216 + P1_GRID, 256, 0, stream>>>(W[0], W[1], W[2], Wc, ei,
                                                  Wsw0, Wsw1, Wsw2, Wcsw, bcnt);

    // ---- CSR build (bucketed) ----
    bscan<<<1, 256, 0, stream>>>(bcnt, bbase, bcur);
    bucket_p1<<<P1_GRID, 256, 0, stream>>>(ei, bcur, tmp);
    bucket_p2a<<<NBUCK, 256, 0, stream>>>(tmp, bbase, rowptr, dinv);
    bucket_p2b<<<NBUCK, 256, 0, stream>>>(tmp, rowptr, dinv, rec);

    const int gemm_grid = (N_NODES + 63) / 64;    // 1563
    const int cls_grid  = (N_NODES + 127) / 128;  // 782
    const int agg_grid  = N_NODES / 4;            // 25000

    // layer 0: x fp32 -> Hh; agg -> Ch
    gemm_mfma_f<<<gemm_grid, 256, 0, stream>>>(x, Wsw0, Hh);
    agg_ln<<<agg_grid, 256, 0, stream>>>(Hh, nullptr, dinv, b[0], g[0], be[0], rowptr, rec, Ch);

    // layer 1: Ch -> Hh; agg (+resid Ch) -> Ah
    gemm_mfma_h<<<gemm_grid, 256, 0, stream>>>(Ch, Wsw1, Hh);
    agg_ln<<<agg_grid, 256, 0, stream>>>(Hh, Ch, dinv, b[1], g[1], be[1], rowptr, rec, Ah);

    // layer 2: Ah -> Hh; agg (+resid Ah) -> Ch
    gemm_mfma_h<<<gemm_grid, 256, 0, stream>>>(Ah, Wsw2, Hh);
    agg_ln<<<agg_grid, 256, 0, stream>>>(Hh, Ah, dinv, b[2], g[2], be[2], rowptr, rec, Ch);

    classifier_mfma<<<cls_grid, 256, 0, stream>>>(Ch, Wcsw, bc, out);
}

// Round 16
// 423.018 us; speedup vs baseline: 1.0069x; 1.0069x over previous
//
#include <hip/hip_runtime.h>
#include <math.h>

#define N_NODES 100000
#define N_EDGES 1600000
#define DIM     128
#define NCLS    40
#define NBUCK   196      // ceil(100000/512) buckets of 512 nodes
#define P1_CH   4096     // edges per phase-1 block
#define P1_GRID 391      // ceil(1600000/4096)

typedef _Float16 f16x8 __attribute__((ext_vector_type(8)));
typedef _Float16 f16x2 __attribute__((ext_vector_type(2)));
typedef float    f32x4 __attribute__((ext_vector_type(4)));

__device__ inline unsigned short f16bits(float f) {
    union { _Float16 h; unsigned short u; } cv;
    cv.h = (_Float16)f;
    return cv.u;
}
__device__ inline f16x2 as_h2(unsigned u) {
    union { unsigned u; f16x2 h; } cv;
    cv.u = u;
    return cv.h;
}
__device__ inline unsigned as_u(f16x2 h) {
    union { f16x2 h; unsigned u; } cv;
    cv.h = h;
    return cv.u;
}
__device__ inline unsigned pack_h2(float lo, float hi) {
    f16x2 h;
    h.x = (_Float16)lo;
    h.y = (_Float16)hi;
    return as_u(h);
}
__device__ inline int wave_incl_scan(int v, int lane) {
#pragma unroll
    for (int off = 1; off < 64; off <<= 1) {
        int x = __shfl_up(v, off, 64);
        if (lane >= off) v += x;
    }
    return v;
}

// ---------------------------------------------------------------- setup: W swizzles + bucket histogram (bcnt pre-zeroed)
// blocks 0..191: Wsw0/1/2; 192..215: Wcsw; 216..606: bhist
__global__ __launch_bounds__(256) void setup_misc(const float* __restrict__ W0,
                                                  const float* __restrict__ W1,
                                                  const float* __restrict__ W2,
                                                  const float* __restrict__ Wc,
                                                  const int* __restrict__ ei,
                                                  unsigned short* __restrict__ Wsw0,
                                                  unsigned short* __restrict__ Wsw1,
                                                  unsigned short* __restrict__ Wsw2,
                                                  unsigned short* __restrict__ Wcsw,
                                                  int* __restrict__ bcnt) {
    int blk = blockIdx.x;
    if (blk < 192) {
        const float* W = (blk < 64) ? W0 : (blk < 128) ? W1 : W2;
        unsigned short* Wsw = (blk < 64) ? Wsw0 : (blk < 128) ? Wsw1 : Wsw2;
        int o = (blk & 63) * 256 + threadIdx.x;  // 0..16383
        int f = o >> 9;
        int l = (o >> 3) & 63;
        int j = o & 7;
        int n = f >> 2;
        int s = f & 3;
        int k = s * 32 + (l >> 4) * 8 + j;
        int c = (l & 15) * 8 + n;
        Wsw[o] = f16bits(W[k * DIM + c]);
    } else if (blk < 216) {
        int o = (blk - 192) * 256 + threadIdx.x; // 0..6143
        int f = o >> 9;
        int l = (o >> 3) & 63;
        int j = o & 7;
        int n = f >> 2;
        int s = f & 3;
        int k = s * 32 + (l >> 4) * 8 + j;
        int c = (l & 15) * 3 + n;
        Wcsw[o] = (c < NCLS) ? f16bits(Wc[k * NCLS + c]) : (unsigned short)0;
    } else {
        __shared__ int h[256];
        const int t  = threadIdx.x;
        const int e0 = (blk - 216) * P1_CH;
        const int cnt = min(P1_CH, N_EDGES - e0);
        h[t] = 0;
        __syncthreads();
        for (int i = t; i < cnt; i += 256)
            atomicAdd(&h[ei[N_EDGES + e0 + i] >> 9], 1);
        __syncthreads();
        if (h[t]) atomicAdd(&bcnt[t], h[t]);
    }
}

// ---------------------------------------------------------------- bucket scan (1 block): bbase (exclusive), bcur = bbase
__global__ __launch_bounds__(256) void bscan(const int* __restrict__ bcnt,
                                             int* __restrict__ bbase,
                                             int* __restrict__ bcur) {
    __shared__ int wtot[4];
    int t = threadIdx.x;
    int lane = t & 63, wv = t >> 6;
    int v = (t < NBUCK) ? bcnt[t] : 0;
    int incl = wave_incl_scan(v, lane);
    if (lane == 63) wtot[wv] = incl;
    __syncthreads();
    int prefix = 0;
    for (int i = 0; i < wv; ++i) prefix += wtot[i];
    incl += prefix;
    int excl = incl - v;
    if (t < NBUCK) {
        bbase[t] = excl;
        bcur[t]  = excl;
    }
    if (t == 0) bbase[NBUCK] = N_EDGES;
}

// ---------------------------------------------------------------- phase 1: bucket edges by dst>>9 into packed tmp
// tmp entry = (s<<9) | (d & 511)   (17+9 = 26 bits)
__global__ __launch_bounds__(256) void bucket_p1(const int* __restrict__ ei,
                                                 int* __restrict__ bcur,
                                                 unsigned* __restrict__ tmp) {
    __shared__ int  hist[256];
    __shared__ int  lscan[256];
    __shared__ int  rank[256];
    __shared__ int  gbase[256];
    __shared__ int  wtot[4];
    __shared__ int2 stage[P1_CH];      // 32 KB
    const int t  = threadIdx.x;
    const int lane = t & 63, wv = t >> 6;
    const int e0 = blockIdx.x * P1_CH;
    const int cnt = min(P1_CH, N_EDGES - e0);

    hist[t] = 0;
    __syncthreads();

    int2 ed[16];
#pragma unroll
    for (int i = 0; i < 16; ++i) {
        int idx = t + i * 256;
        if (idx < cnt) {
            int s = ei[e0 + idx];
            int d = ei[N_EDGES + e0 + idx];
            ed[i] = make_int2(s, d);
            atomicAdd(&hist[d >> 9], 1);
        }
    }
    __syncthreads();

    int hv = hist[t];
    int incl = wave_incl_scan(hv, lane);
    if (lane == 63) wtot[wv] = incl;
    __syncthreads();
    int prefix = 0;
    for (int i = 0; i < wv; ++i) prefix += wtot[i];
    incl += prefix;
    int excl = incl - hv;
    lscan[t] = excl;
    rank[t]  = excl;
    if (hv > 0) gbase[t] = atomicAdd(&bcur[t], hv);
    __syncthreads();

#pragma unroll
    for (int i = 0; i < 16; ++i) {
        int idx = t + i * 256;
        if (idx < cnt) {
            int b = ed[i].y >> 9;
            int p = atomicAdd(&rank[b], 1);
            stage[p] = ed[i];
        }
    }
    __syncthreads();

    for (int p = t; p < cnt; p += 256) {
        int2 v = stage[p];
        int b = v.y >> 9;
        tmp[gbase[b] + (p - lscan[b])] = ((unsigned)v.x << 9) | ((unsigned)v.y & 511u);
    }
}

// ---------------------------------------------------------------- phase 2a: per-bucket node counts (LDS) -> rowptr + dinv
__global__ __launch_bounds__(256) void bucket_p2a(const unsigned* __restrict__ tmp,
                                                  const int* __restrict__ bbase,
                                                  int* __restrict__ rowptr,
                                                  float* __restrict__ dinv) {
    __shared__ int cnt[512];
    __shared__ int wtot[4];
    const int t  = threadIdx.x;
    const int lane = t & 63, wv = t >> 6;
    const int b  = blockIdx.x;
    const int d0 = b << 9;
    const int dend = min(d0 + 512, N_NODES);
    const int nn = dend - d0;

    cnt[t] = 0;
    cnt[t + 256] = 0;
    __syncthreads();

    const int beg = bbase[b];
    const int end = bbase[b + 1];
    for (int idx = beg + t; idx < end; idx += 256)
        atomicAdd(&cnt[tmp[idx] & 511u], 1);
    __syncthreads();

    int c0 = cnt[2 * t];
    int c1 = cnt[2 * t + 1];
    int pv = c0 + c1;
    int incl = wave_incl_scan(pv, lane);
    if (lane == 63) wtot[wv] = incl;
    __syncthreads();
    int prefix = 0;
    for (int i = 0; i < wv; ++i) prefix += wtot[i];
    incl += prefix;
    int excl = incl - pv;
    if (2 * t < nn) {
        rowptr[d0 + 2 * t] = beg + excl;
        dinv[d0 + 2 * t]   = rsqrtf((float)c0 + 1.0f);
    }
    if (2 * t + 1 < nn) {
        rowptr[d0 + 2 * t + 1] = beg + excl + c0;
        dinv[d0 + 2 * t + 1]   = rsqrtf((float)c1 + 1.0f);
    }
    if (b == NBUCK - 1 && t == 0) rowptr[N_NODES] = N_EDGES;
}

// ---------------------------------------------------------------- phase 2b: within-bucket scatter; rec = (src*256, half2(w,w))
__global__ __launch_bounds__(256) void bucket_p2b(const unsigned* __restrict__ tmp,
                                                  const int* __restrict__ rowptr,
                                                  const float* __restrict__ dinv,
                                                  int2* __restrict__ rec) {
    __shared__ int   cur[512];
    __shared__ float dinvL[512];
    const int t  = threadIdx.x;
    const int b  = blockIdx.x;
    const int d0 = b << 9;
    const int dend = min(d0 + 512, N_NODES);
    const int nn = dend - d0;

    for (int i = t; i < nn; i += 256) {
        cur[i]   = rowptr[d0 + i];
        dinvL[i] = dinv[d0 + i];
    }
    __syncthreads();

    const int beg = rowptr[d0];
    const int end = rowptr[dend];
    for (int idx = beg + t; idx < end; idx += 256) {
        unsigned u = tmp[idx];
        int s  = (int)(u >> 9);
        int dl = (int)(u & 511u);
        int pos = atomicAdd(&cur[dl], 1);
        unsigned short wb = f16bits(dinv[s] * dinvL[dl]);
        rec[pos] = make_int2(s << 8, (int)((unsigned)wb | ((unsigned)wb << 16)));
    }
}

// ---------------------------------------------------------------- MFMA GEMM, fp32 input (layer 0): 16 rows/wave, W frags from LDS
__global__ __launch_bounds__(256) void gemm_mfma_f(const float* __restrict__ X,
                                                   const unsigned short* __restrict__ Wsw,
                                                   unsigned short* __restrict__ H) {
    __shared__ unsigned short wlds[32 * 512];   // 32 KB
    const int tid   = threadIdx.x;
    const int lane  = tid & 63;
    const int wave  = tid >> 6;
    const int row0w = blockIdx.x * 64 + wave * 16;
    const int m = lane & 15;
    const int q = lane >> 4;

    {
        const uint4* srcp = (const uint4*)Wsw;
        uint4*       dstp = (uint4*)wlds;
#pragma unroll
        for (int i = 0; i < 8; ++i) dstp[tid + i * 256] = srcp[tid + i * 256];
    }
    __syncthreads();

    int r = row0w + m;
    if (r >= N_NODES) r = N_NODES - 1;
    const float* xp = X + (size_t)r * DIM + q * 8;
    f16x8 af[4];
#pragma unroll
    for (int s = 0; s < 4; ++s) {
        float4 x0 = *(const float4*)(xp + s * 32);
        float4 x1 = *(const float4*)(xp + s * 32 + 4);
        f16x8 v;
        v[0] = (_Float16)x0.x; v[1] = (_Float16)x0.y;
        v[2] = (_Float16)x0.z; v[3] = (_Float16)x0.w;
        v[4] = (_Float16)x1.x; v[5] = (_Float16)x1.y;
        v[6] = (_Float16)x1.z; v[7] = (_Float16)x1.w;
        af[s] = v;
    }

    f32x4 acc[8];
    f32x4 z = {0.f, 0.f, 0.f, 0.f};
#pragma unroll
    for (int n = 0; n < 8; ++n) acc[n] = z;

    const unsigned short* wl = wlds + lane * 8;
#pragma unroll
    for (int s = 0; s < 4; ++s)
#pragma unroll
        for (int n = 0; n < 8; ++n) {
            f16x8 wf = *(const f16x8*)(wl + ((n * 4 + s) << 9));
            acc[n] = __builtin_amdgcn_mfma_f32_16x16x32_f16(af[s], wf, acc[n], 0, 0, 0);
        }

#pragma unroll
    for (int j = 0; j < 4; ++j) {
        int row = row0w + q * 4 + j;
        if (row < N_NODES) {
            uint4 o;
            o.x = pack_h2(acc[0][j], acc[1][j]);
            o.y = pack_h2(acc[2][j], acc[3][j]);
            o.z = pack_h2(acc[4][j], acc[5][j]);
            o.w = pack_h2(acc[6][j], acc[7][j]);
            *(uint4*)(H + (size_t)row * DIM + m * 8) = o;
        }
    }
}

// ---------------------------------------------------------------- MFMA GEMM, f16 input (layers 1,2): 16 rows/wave, W frags from LDS
__global__ __launch_bounds__(256) void gemm_mfma_h(const unsigned short* __restrict__ Xh,
                                                   const unsigned short* __restrict__ Wsw,
                                                   unsigned short* __restrict__ H) {
    __shared__ unsigned short wlds[32 * 512];   // 32 KB
    const int tid   = threadIdx.x;
    const int lane  = tid & 63;
    const int wave  = tid >> 6;
    const int row0w = blockIdx.x * 64 + wave * 16;
    const int m = lane & 15;
    const int q = lane >> 4;

    {
        const uint4* srcp = (const uint4*)Wsw;
        uint4*       dstp = (uint4*)wlds;
#pragma unroll
        for (int i = 0; i < 8; ++i) dstp[tid + i * 256] = srcp[tid + i * 256];
    }
    __syncthreads();

    int r = row0w + m;
    if (r >= N_NODES) r = N_NODES - 1;
    const unsigned short* xp = Xh + (size_t)r * DIM + q * 8;
    f16x8 af[4];
#pragma unroll
    for (int s = 0; s < 4; ++s) af[s] = *(const f16x8*)(xp + s * 32);

    f32x4 acc[8];
    f32x4 z = {0.f, 0.f, 0.f, 0.f};
#pragma unroll
    for (int n = 0; n < 8; ++n) acc[n] = z;

    const unsigned short* wl = wlds + lane * 8;
#pragma unroll
    for (int s = 0; s < 4; ++s)
#pragma unroll
        for (int n = 0; n < 8; ++n) {
            f16x8 wf = *(const f16x8*)(wl + ((n * 4 + s) << 9));
            acc[n] = __builtin_amdgcn_mfma_f32_16x16x32_f16(af[s], wf, acc[n], 0, 0, 0);
        }

#pragma unroll
    for (int j = 0; j < 4; ++j) {
        int row = row0w + q * 4 + j;
        if (row < N_NODES) {
            uint4 o;
            o.x = pack_h2(acc[0][j], acc[1][j]);
            o.y = pack_h2(acc[2][j], acc[3][j]);
            o.z = pack_h2(acc[4][j], acc[5][j]);
            o.w = pack_h2(acc[6][j], acc[7][j]);
            *(uint4*)(H + (size_t)row * DIM + m * 8) = o;
        }
    }
}

// ---------------------------------------------------------------- fused gather-aggregate + LN + ELU (+ residual), f16
__global__ __launch_bounds__(256) void agg_ln(const unsigned short* __restrict__ Hh,
                                              const unsigned short* __restrict__ xin,
                                              const float* __restrict__ dinv,
                                              const float* __restrict__ bias,
                                              const float* __restrict__ g,
                                              const float* __restrict__ be,
                                              const int* __restrict__ rowptr,
                                              const int2* __restrict__ rec,
                                              unsigned short* __restrict__ outb) {
    int node = blockIdx.x * 4 + (threadIdx.x >> 6);
    int lane = threadIdx.x & 63;
    int sub  = lane & 15;
    int qtr  = lane >> 4;
    int beg = rowptr[node];
    int end = rowptr[node + 1];
    const char* Hb8 = (const char*)Hh;
    const unsigned laneoff = (unsigned)sub * 16;   // byte offset within row

    f16x2 acc[4];
    f16x2 hz = {(_Float16)0.f, (_Float16)0.f};
#pragma unroll
    for (int k = 0; k < 4; ++k) acc[k] = hz;

    for (int e0 = beg; e0 < end; e0 += 64) {
        int cnt = min(end - e0, 64);
        int2 rc = (lane < cnt) ? rec[e0 + lane] : make_int2(0, 0);
        int sv = rc.x;                        // src*256 byte offset (pads have w=0)
        int wv = rc.y;                        // packed half2 (w,w)
        int cntR = (cnt + 15) & ~15;
        for (int j = 0; j < cntR; j += 16) {
            int i0 = j + qtr, i1 = j + 4 + qtr, i2 = j + 8 + qtr, i3 = j + 12 + qtr;
            unsigned o0 = (unsigned)__shfl(sv, i0, 64) + laneoff;
            int      w0 = __shfl(wv, i0, 64);
            unsigned o1 = (unsigned)__shfl(sv, i1, 64) + laneoff;
            int      w1 = __shfl(wv, i1, 64);
            unsigned o2 = (unsigned)__shfl(sv, i2, 64) + laneoff;
            int      w2 = __shfl(wv, i2, 64);
            unsigned o3 = (unsigned)__shfl(sv, i3, 64) + laneoff;
            int      w3 = __shfl(wv, i3, 64);
            uint4 u0 = *(const uint4*)(Hb8 + o0);
            uint4 u1 = *(const uint4*)(Hb8 + o1);
            uint4 u2 = *(const uint4*)(Hb8 + o2);
            uint4 u3 = *(const uint4*)(Hb8 + o3);
            f16x2 hw0 = as_h2(w0), hw1 = as_h2(w1), hw2 = as_h2(w2), hw3 = as_h2(w3);
            acc[0] += as_h2(u0.x) * hw0;
            acc[1] += as_h2(u0.y) * hw0;
            acc[2] += as_h2(u0.z) * hw0;
            acc[3] += as_h2(u0.w) * hw0;
            acc[0] += as_h2(u1.x) * hw1;
            acc[1] += as_h2(u1.y) * hw1;
            acc[2] += as_h2(u1.z) * hw1;
            acc[3] += as_h2(u1.w) * hw1;
            acc[0] += as_h2(u2.x) * hw2;
            acc[1] += as_h2(u2.y) * hw2;
            acc[2] += as_h2(u2.z) * hw2;
            acc[3] += as_h2(u2.w) * hw2;
            acc[0] += as_h2(u3.x) * hw3;
            acc[1] += as_h2(u3.y) * hw3;
            acc[2] += as_h2(u3.z) * hw3;
            acc[3] += as_h2(u3.w) * hw3;
        }
    }

#pragma unroll
    for (int k = 0; k < 4; ++k) {
        acc[k] += as_h2(__shfl_xor(as_u(acc[k]), 16, 64));
        acc[k] += as_h2(__shfl_xor(as_u(acc[k]), 32, 64));
    }

    unsigned mu = as_u(acc[0]);
    mu = (qtr == 1) ? as_u(acc[1]) : mu;
    mu = (qtr == 2) ? as_u(acc[2]) : mu;
    mu = (qtr == 3) ? as_u(acc[3]) : mu;
    f16x2 mine = as_h2(mu);
    const int c0 = sub * 8 + qtr * 2;
    const unsigned nodeoff = ((unsigned)node << 8) + (unsigned)c0 * 2;

    float dv = dinv[node];
    float d2 = dv * dv;
    f16x2 hh = as_h2(*(const unsigned*)(Hb8 + nodeoff));
    float2 bb = *(const float2*)(bias + c0);
    float a0 = (float)mine.x + (float)hh.x * d2 + bb.x;
    float a1 = (float)mine.y + (float)hh.y * d2 + bb.y;

    float s1 = a0 + a1;
    float s2 = a0 * a0 + a1 * a1;
#pragma unroll
    for (int mk = 1; mk <= 32; mk <<= 1) {
        s1 += __shfl_xor(s1, mk, 64);
        s2 += __shfl_xor(s2, mk, 64);
    }
    float mean = s1 * (1.0f / 128.0f);
    float var  = s2 * (1.0f / 128.0f) - mean * mean;
    float rr   = rsqrtf(var + 1e-5f);
    float2 gg = *(const float2*)(g + c0);
    float2 ee = *(const float2*)(be + c0);
    float r0 = (a0 - mean) * rr * gg.x + ee.x;
    float r1 = (a1 - mean) * rr * gg.y + ee.y;
    r0 = r0 > 0.0f ? r0 : expm1f(r0);
    r1 = r1 > 0.0f ? r1 : expm1f(r1);
    if (xin) {
        f16x2 xi = as_h2(*(const unsigned*)((const char*)xin + nodeoff));
        r0 += (float)xi.x;
        r1 += (float)xi.y;
    }
    *(unsigned*)((char*)outb + nodeoff) = pack_h2(r0, r1);
}

// ---------------------------------------------------------------- MFMA classifier, f16 input: 32 rows/wave, Wc via LDS
__global__ __launch_bounds__(256) void classifier_mfma(const unsigned short* __restrict__ Xh,
                                                       const unsigned short* __restrict__ Wcsw,
                                                       const float* __restrict__ bc,
                                                       float* __restrict__ out) {
    __shared__ unsigned short wlds[12 * 512];   // 12 KB
    const int tid   = threadIdx.x;
    const int lane  = tid & 63;
    const int wave  = tid >> 6;
    const int row0w = blockIdx.x * 128 + wave * 32;
    const int m = lane & 15;
    const int q = lane >> 4;

    {
        const uint4* srcp = (const uint4*)Wcsw;
        uint4*       dstp = (uint4*)wlds;
#pragma unroll
        for (int i = 0; i < 3; ++i) dstp[tid + i * 256] = srcp[tid + i * 256];
    }
    __syncthreads();

    f16x8 wf[12];
#pragma unroll
    for (int f = 0; f < 12; ++f)
        wf[f] = *(const f16x8*)(wlds + (f << 9) + lane * 8);

    f16x8 af[2][4];
#pragma unroll
    for (int ggr = 0; ggr < 2; ++ggr) {
        int r = row0w + ggr * 16 + m;
        if (r >= N_NODES) r = N_NODES - 1;
        const unsigned short* xp = Xh + (size_t)r * DIM + q * 8;
#pragma unroll
        for (int s = 0; s < 4; ++s) af[ggr][s] = *(const f16x8*)(xp + s * 32);
    }

    f32x4 acc[2][3];
    f32x4 z = {0.f, 0.f, 0.f, 0.f};
#pragma unroll
    for (int ggr = 0; ggr < 2; ++ggr)
#pragma unroll
        for (int n = 0; n < 3; ++n) acc[ggr][n] = z;

#pragma unroll
    for (int s = 0; s < 4; ++s)
#pragma unroll
        for (int n = 0; n < 3; ++n) {
            acc[0][n] = __builtin_amdgcn_mfma_f32_16x16x32_f16(af[0][s], wf[n * 4 + s], acc[0][n], 0, 0, 0);
            acc[1][n] = __builtin_amdgcn_mfma_f32_16x16x32_f16(af[1][s], wf[n * 4 + s], acc[1][n], 0, 0, 0);
        }

    float bcv[3];
#pragma unroll
    for (int n = 0; n < 3; ++n) {
        int c = 3 * m + n;
        bcv[n] = (c < NCLS) ? bc[c] : 0.f;
    }

#pragma unroll
    for (int ggr = 0; ggr < 2; ++ggr)
#pragma unroll
        for (int j = 0; j < 4; ++j) {
            int row = row0w + ggr * 16 + q * 4 + j;
            if (row < N_NODES) {
#pragma unroll
                for (int n = 0; n < 3; ++n) {
                    int c = 3 * m + n;
                    if (c < NCLS)
                        out[(size_t)row * NCLS + c] = acc[ggr][n][j] + bcv[n];
                }
            }
        }
}

// ---------------------------------------------------------------- launch
extern "C" void kernel_launch(void* const* d_in, const int* in_sizes, int n_in,
                              void* d_out, int out_size, void* d_ws, size_t ws_size,
                              hipStream_t stream) {
    const float* x  = (const float*)d_in[0];
    const int*   ei = (const int*)d_in[1];
    const float* W[3]  = {(const float*)d_in[2], (const float*)d_in[6], (const float*)d_in[10]};
    const float* b[3]  = {(const float*)d_in[3], (const float*)d_in[7], (const float*)d_in[11]};
    const float* g[3]  = {(const float*)d_in[4], (const float*)d_in[8], (const float*)d_in[12]};
    const float* be[3] = {(const float*)d_in[5], (const float*)d_in[9], (const float*)d_in[13]};
    const float* Wc = (const float*)d_in[14];
    const float* bc = (const float*)d_in[15];
    float* out = (float*)d_out;

    char* ws = (char*)d_ws;
    const size_t NP = 400128;  // padded (N+1)*4 bytes
    float* dinv   = (float*)(ws);
    int*   rowptr = (int*)  (ws + NP);
    int*   bcnt   = (int*)  (ws + 2 * NP);
    int*   bbase  = (int*)  (ws + 2 * NP + 1024);
    int*   bcur   = (int*)  (ws + 2 * NP + 2048);
    int2*  rec    = (int2*) (ws + 2 * NP + 4096);
    unsigned short* Hh = (unsigned short*)(ws + 2 * NP + 4096 + (size_t)N_EDGES * 8);
    unsigned short* Ah = Hh + (size_t)N_NODES * DIM;
    unsigned short* Ch = Ah + (size_t)N_NODES * DIM;
    unsigned short* Wsw0 = Ch + (size_t)N_NODES * DIM;
    unsigned short* Wsw1 = Wsw0 + DIM * DIM;
    unsigned short* Wsw2 = Wsw1 + DIM * DIM;
    unsigned short* Wcsw = Wsw2 + DIM * DIM;   // 12*512 shorts
    unsigned* tmp = (unsigned*)Ch;             // aliases Ch; dead before layer 0 writes Ch

    // ---- setup: zero bcnt (memset) + swizzles + bucket histogram (1 dispatch) ----
    hipMemsetAsync(bcnt, 0, 1024, stream);
    setup_misc<<<216 + P1_GRID, 256, 0, stream>>>(W[0], W[1], W[2], Wc, ei,
                                                  Wsw0, Wsw1, Wsw2, Wcsw, bcnt);

    // ---- CSR build (bucketed, packed tmp) ----
    bscan<<<1, 256, 0, stream>>>(bcnt, bbase, bcur);
    bucket_p1<<<P1_GRID, 256, 0, stream>>>(ei, bcur, tmp);
    bucket_p2a<<<NBUCK, 256, 0, stream>>>(tmp, bbase, rowptr, dinv);
    bucket_p2b<<<NBUCK, 256, 0, stream>>>(tmp, rowptr, dinv, rec);

    const int gemm_grid = (N_NODES + 63) / 64;    // 1563
    const int cls_grid  = (N_NODES + 127) / 128;  // 782
    const int agg_grid  = N_NODES / 4;            // 25000

    // layer 0: x fp32 -> Hh; agg -> Ch
    gemm_mfma_f<<<gemm_grid, 256, 0, stream>>>(x, Wsw0, Hh);
    agg_ln<<<agg_grid, 256, 0, stream>>>(Hh, nullptr, dinv, b[0], g[0], be[0], rowptr, rec, Ch);

    // layer 1: Ch -> Hh; agg (+resid Ch) -> Ah
    gemm_mfma_h<<<gemm_grid, 256, 0, stream>>>(Ch, Wsw1, Hh);
    agg_ln<<<agg_grid, 256, 0, stream>>>(Hh, Ch, dinv, b[1], g[1], be[1], rowptr, rec, Ah);

    // layer 2: Ah -> Hh; agg (+resid Ah) -> Ch
    gemm_mfma_h<<<gemm_grid, 256, 0, stream>>>(Ah, Wsw2, Hh);
    agg_ln<<<agg_grid, 256, 0, stream>>>(Hh, Ah, dinv, b[2], g[2], be[2], rowptr, rec, Ch);

    classifier_mfma<<<cls_grid, 256, 0, stream>>>(Ch, Wcsw, bc, out);
}

// Round 17
// 411.304 us; speedup vs baseline: 1.0356x; 1.0285x over previous
//
#include <hip/hip_runtime.h>
#include <math.h>

#define N_NODES 100000
#define N_EDGES 1600000
#define DIM     128
#define NCLS    40
#define NBUCK   196      // ceil(100000/512) buckets of 512 nodes
#define P1_CH   4096     // edges per phase-1 block
#define P1_GRID 391      // ceil(1600000/4096)

typedef _Float16 f16x8 __attribute__((ext_vector_type(8)));
typedef _Float16 f16x2 __attribute__((ext_vector_type(2)));
typedef float    f32x4 __attribute__((ext_vector_type(4)));

__device__ inline unsigned short f16bits(float f) {
    union { _Float16 h; unsigned short u; } cv;
    cv.h = (_Float16)f;
    return cv.u;
}
__device__ inline f16x2 as_h2(unsigned u) {
    union { unsigned u; f16x2 h; } cv;
    cv.u = u;
    return cv.h;
}
__device__ inline unsigned as_u(f16x2 h) {
    union { f16x2 h; unsigned u; } cv;
    cv.h = h;
    return cv.u;
}
__device__ inline unsigned pack_h2(float lo, float hi) {
    f16x2 h;
    h.x = (_Float16)lo;
    h.y = (_Float16)hi;
    return as_u(h);
}
__device__ inline int wave_incl_scan(int v, int lane) {
#pragma unroll
    for (int off = 1; off < 64; off <<= 1) {
        int x = __shfl_up(v, off, 64);
        if (lane >= off) v += x;
    }
    return v;
}

// ---------------------------------------------------------------- setup: W swizzles + bucket histogram (bcnt pre-zeroed)
__global__ __launch_bounds__(256) void setup_misc(const float* __restrict__ W0,
                                                  const float* __restrict__ W1,
                                                  const float* __restrict__ W2,
                                                  const float* __restrict__ Wc,
                                                  const int* __restrict__ ei,
                                                  unsigned short* __restrict__ Wsw0,
                                                  unsigned short* __restrict__ Wsw1,
                                                  unsigned short* __restrict__ Wsw2,
                                                  unsigned short* __restrict__ Wcsw,
                                                  int* __restrict__ bcnt) {
    int blk = blockIdx.x;
    if (blk < 192) {
        const float* W = (blk < 64) ? W0 : (blk < 128) ? W1 : W2;
        unsigned short* Wsw = (blk < 64) ? Wsw0 : (blk < 128) ? Wsw1 : Wsw2;
        int o = (blk & 63) * 256 + threadIdx.x;  // 0..16383
        int f = o >> 9;
        int l = (o >> 3) & 63;
        int j = o & 7;
        int n = f >> 2;
        int s = f & 3;
        int k = s * 32 + (l >> 4) * 8 + j;
        int c = (l & 15) * 8 + n;
        Wsw[o] = f16bits(W[k * DIM + c]);
    } else if (blk < 216) {
        int o = (blk - 192) * 256 + threadIdx.x; // 0..6143
        int f = o >> 9;
        int l = (o >> 3) & 63;
        int j = o & 7;
        int n = f >> 2;
        int s = f & 3;
        int k = s * 32 + (l >> 4) * 8 + j;
        int c = (l & 15) * 3 + n;
        Wcsw[o] = (c < NCLS) ? f16bits(Wc[k * NCLS + c]) : (unsigned short)0;
    } else {
        __shared__ int h[256];
        const int t  = threadIdx.x;
        const int e0 = (blk - 216) * P1_CH;
        const int cnt = min(P1_CH, N_EDGES - e0);
        h[t] = 0;
        __syncthreads();
        for (int i = t; i < cnt; i += 256)
            atomicAdd(&h[ei[N_EDGES + e0 + i] >> 9], 1);
        __syncthreads();
        if (h[t]) atomicAdd(&bcnt[t], h[t]);
    }
}

// ---------------------------------------------------------------- bucket scan (1 block): bbase (exclusive), bcur = bbase
__global__ __launch_bounds__(256) void bscan(const int* __restrict__ bcnt,
                                             int* __restrict__ bbase,
                                             int* __restrict__ bcur) {
    __shared__ int wtot[4];
    int t = threadIdx.x;
    int lane = t & 63, wv = t >> 6;
    int v = (t < NBUCK) ? bcnt[t] : 0;
    int incl = wave_incl_scan(v, lane);
    if (lane == 63) wtot[wv] = incl;
    __syncthreads();
    int prefix = 0;
    for (int i = 0; i < wv; ++i) prefix += wtot[i];
    incl += prefix;
    int excl = incl - v;
    if (t < NBUCK) {
        bbase[t] = excl;
        bcur[t]  = excl;
    }
    if (t == 0) bbase[NBUCK] = N_EDGES;
}

// ---------------------------------------------------------------- phase 1: bucket edges by dst>>9 into packed tmp
// tmp entry = (s<<9) | (d & 511)
__global__ __launch_bounds__(256) void bucket_p1(const int* __restrict__ ei,
                                                 int* __restrict__ bcur,
                                                 unsigned* __restrict__ tmp) {
    __shared__ int  hist[256];
    __shared__ int  lscan[256];
    __shared__ int  rank[256];
    __shared__ int  gbase[256];
    __shared__ int  wtot[4];
    __shared__ int2 stage[P1_CH];      // 32 KB
    const int t  = threadIdx.x;
    const int lane = t & 63, wv = t >> 6;
    const int e0 = blockIdx.x * P1_CH;
    const int cnt = min(P1_CH, N_EDGES - e0);

    hist[t] = 0;
    __syncthreads();

    int2 ed[16];
#pragma unroll
    for (int i = 0; i < 16; ++i) {
        int idx = t + i * 256;
        if (idx < cnt) {
            int s = ei[e0 + idx];
            int d = ei[N_EDGES + e0 + idx];
            ed[i] = make_int2(s, d);
            atomicAdd(&hist[d >> 9], 1);
        }
    }
    __syncthreads();

    int hv = hist[t];
    int incl = wave_incl_scan(hv, lane);
    if (lane == 63) wtot[wv] = incl;
    __syncthreads();
    int prefix = 0;
    for (int i = 0; i < wv; ++i) prefix += wtot[i];
    incl += prefix;
    int excl = incl - hv;
    lscan[t] = excl;
    rank[t]  = excl;
    if (hv > 0) gbase[t] = atomicAdd(&bcur[t], hv);
    __syncthreads();

#pragma unroll
    for (int i = 0; i < 16; ++i) {
        int idx = t + i * 256;
        if (idx < cnt) {
            int b = ed[i].y >> 9;
            int p = atomicAdd(&rank[b], 1);
            stage[p] = ed[i];
        }
    }
    __syncthreads();

    for (int p = t; p < cnt; p += 256) {
        int2 v = stage[p];
        int b = v.y >> 9;
        tmp[gbase[b] + (p - lscan[b])] = ((unsigned)v.x << 9) | ((unsigned)v.y & 511u);
    }
}

// ---------------------------------------------------------------- phase 2 (fused): counts -> rowptr+dinv, then scatter rec=src<<8
__global__ __launch_bounds__(256) void bucket_p2(const unsigned* __restrict__ tmp,
                                                 const int* __restrict__ bbase,
                                                 int* __restrict__ rowptr,
                                                 float* __restrict__ dinv,
                                                 unsigned* __restrict__ rec) {
    __shared__ int cnt[512];
    __shared__ int cur[512];
    __shared__ int wtot[4];
    const int t  = threadIdx.x;
    const int lane = t & 63, wv = t >> 6;
    const int b  = blockIdx.x;
    const int d0 = b << 9;
    const int dend = min(d0 + 512, N_NODES);
    const int nn = dend - d0;

    cnt[t] = 0;
    cnt[t + 256] = 0;
    __syncthreads();

    const int beg = bbase[b];
    const int end = bbase[b + 1];
    for (int idx = beg + t; idx < end; idx += 256)
        atomicAdd(&cnt[tmp[idx] & 511u], 1);
    __syncthreads();

    int c0 = cnt[2 * t];
    int c1 = cnt[2 * t + 1];
    int pv = c0 + c1;
    int incl = wave_incl_scan(pv, lane);
    if (lane == 63) wtot[wv] = incl;
    __syncthreads();
    int prefix = 0;
    for (int i = 0; i < wv; ++i) prefix += wtot[i];
    incl += prefix;
    int excl = incl - pv;
    int base0 = beg + excl;
    int base1 = base0 + c0;
    cur[2 * t]     = base0;
    cur[2 * t + 1] = base1;
    if (2 * t < nn) {
        rowptr[d0 + 2 * t] = base0;
        dinv[d0 + 2 * t]   = rsqrtf((float)c0 + 1.0f);
    }
    if (2 * t + 1 < nn) {
        rowptr[d0 + 2 * t + 1] = base1;
        dinv[d0 + 2 * t + 1]   = rsqrtf((float)c1 + 1.0f);
    }
    if (b == NBUCK - 1 && t == 0) rowptr[N_NODES] = N_EDGES;
    __syncthreads();

    for (int idx = beg + t; idx < end; idx += 256) {
        unsigned u = tmp[idx];
        int pos = atomicAdd(&cur[u & 511u], 1);
        rec[pos] = (u >> 9) << 8;       // src byte-offset
    }
}

// ---------------------------------------------------------------- MFMA GEMM, fp32 input (layer 0): out rows scaled by dinv[row]
__global__ __launch_bounds__(256) void gemm_mfma_f(const float* __restrict__ X,
                                                   const unsigned short* __restrict__ Wsw,
                                                   const float* __restrict__ dinv,
                                                   unsigned short* __restrict__ H) {
    __shared__ unsigned short wlds[32 * 512];   // 32 KB
    const int tid   = threadIdx.x;
    const int lane  = tid & 63;
    const int wave  = tid >> 6;
    const int row0w = blockIdx.x * 64 + wave * 16;
    const int m = lane & 15;
    const int q = lane >> 4;

    {
        const uint4* srcp = (const uint4*)Wsw;
        uint4*       dstp = (uint4*)wlds;
#pragma unroll
        for (int i = 0; i < 8; ++i) dstp[tid + i * 256] = srcp[tid + i * 256];
    }
    __syncthreads();

    int r = row0w + m;
    if (r >= N_NODES) r = N_NODES - 1;
    const float* xp = X + (size_t)r * DIM + q * 8;
    f16x8 af[4];
#pragma unroll
    for (int s = 0; s < 4; ++s) {
        float4 x0 = *(const float4*)(xp + s * 32);
        float4 x1 = *(const float4*)(xp + s * 32 + 4);
        f16x8 v;
        v[0] = (_Float16)x0.x; v[1] = (_Float16)x0.y;
        v[2] = (_Float16)x0.z; v[3] = (_Float16)x0.w;
        v[4] = (_Float16)x1.x; v[5] = (_Float16)x1.y;
        v[6] = (_Float16)x1.z; v[7] = (_Float16)x1.w;
        af[s] = v;
    }

    f32x4 acc[8];
    f32x4 z = {0.f, 0.f, 0.f, 0.f};
#pragma unroll
    for (int n = 0; n < 8; ++n) acc[n] = z;

    const unsigned short* wl = wlds + lane * 8;
#pragma unroll
    for (int s = 0; s < 4; ++s)
#pragma unroll
        for (int n = 0; n < 8; ++n) {
            f16x8 wf = *(const f16x8*)(wl + ((n * 4 + s) << 9));
            acc[n] = __builtin_amdgcn_mfma_f32_16x16x32_f16(af[s], wf, acc[n], 0, 0, 0);
        }

#pragma unroll
    for (int j = 0; j < 4; ++j) {
        int row = row0w + q * 4 + j;
        if (row < N_NODES) {
            float dv = dinv[row];
            uint4 o;
            o.x = pack_h2(acc[0][j] * dv, acc[1][j] * dv);
            o.y = pack_h2(acc[2][j] * dv, acc[3][j] * dv);
            o.z = pack_h2(acc[4][j] * dv, acc[5][j] * dv);
            o.w = pack_h2(acc[6][j] * dv, acc[7][j] * dv);
            *(uint4*)(H + (size_t)row * DIM + m * 8) = o;
        } else {
            uint4 zz = make_uint4(0u, 0u, 0u, 0u);   // zero pad rows (gather sentinel)
            *(uint4*)(H + (size_t)row * DIM + m * 8) = zz;
        }
    }
}

// ---------------------------------------------------------------- MFMA GEMM, f16 input (layers 1,2): out rows scaled by dinv[row]
__global__ __launch_bounds__(256) void gemm_mfma_h(const unsigned short* __restrict__ Xh,
                                                   const unsigned short* __restrict__ Wsw,
                                                   const float* __restrict__ dinv,
                                                   unsigned short* __restrict__ H) {
    __shared__ unsigned short wlds[32 * 512];   // 32 KB
    const int tid   = threadIdx.x;
    const int lane  = tid & 63;
    const int wave  = tid >> 6;
    const int row0w = blockIdx.x * 64 + wave * 16;
    const int m = lane & 15;
    const int q = lane >> 4;

    {
        const uint4* srcp = (const uint4*)Wsw;
        uint4*       dstp = (uint4*)wlds;
#pragma unroll
        for (int i = 0; i < 8; ++i) dstp[tid + i * 256] = srcp[tid + i * 256];
    }
    __syncthreads();

    int r = row0w + m;
    if (r >= N_NODES) r = N_NODES - 1;
    const unsigned short* xp = Xh + (size_t)r * DIM + q * 8;
    f16x8 af[4];
#pragma unroll
    for (int s = 0; s < 4; ++s) af[s] = *(const f16x8*)(xp + s * 32);

    f32x4 acc[8];
    f32x4 z = {0.f, 0.f, 0.f, 0.f};
#pragma unroll
    for (int n = 0; n < 8; ++n) acc[n] = z;

    const unsigned short* wl = wlds + lane * 8;
#pragma unroll
    for (int s = 0; s < 4; ++s)
#pragma unroll
        for (int n = 0; n < 8; ++n) {
            f16x8 wf = *(const f16x8*)(wl + ((n * 4 + s) << 9));
            acc[n] = __builtin_amdgcn_mfma_f32_16x16x32_f16(af[s], wf, acc[n], 0, 0, 0);
        }

#pragma unroll
    for (int j = 0; j < 4; ++j) {
        int row = row0w + q * 4 + j;
        if (row < N_NODES) {
            float dv = dinv[row];
            uint4 o;
            o.x = pack_h2(acc[0][j] * dv, acc[1][j] * dv);
            o.y = pack_h2(acc[2][j] * dv, acc[3][j] * dv);
            o.z = pack_h2(acc[4][j] * dv, acc[5][j] * dv);
            o.w = pack_h2(acc[6][j] * dv, acc[7][j] * dv);
            *(uint4*)(H + (size_t)row * DIM + m * 8) = o;
        } else {
            uint4 zz = make_uint4(0u, 0u, 0u, 0u);
            *(uint4*)(H + (size_t)row * DIM + m * 8) = zz;
        }
    }
}

// ---------------------------------------------------------------- fused gather-aggregate + LN + ELU (+ residual), f16
// Rows pre-scaled by dinv[src]: unweighted gather, one dv multiply at the end.
__global__ __launch_bounds__(256) void agg_ln(const unsigned short* __restrict__ Hh,
                                              const unsigned short* __restrict__ xin,
                                              const float* __restrict__ dinv,
                                              const float* __restrict__ bias,
                                              const float* __restrict__ g,
                                              const float* __restrict__ be,
                                              const int* __restrict__ rowptr,
                                              const unsigned* __restrict__ rec,
                                              unsigned short* __restrict__ outb) {
    int node = blockIdx.x * 4 + (threadIdx.x >> 6);
    int lane = threadIdx.x & 63;
    int sub  = lane & 15;
    int qtr  = lane >> 4;
    int beg = rowptr[node];
    int end = rowptr[node + 1];
    const char* Hb8 = (const char*)Hh;
    const unsigned laneoff = (unsigned)sub * 16;       // byte offset within row
    const unsigned sentin  = (unsigned)N_NODES << 8;   // zero row

    f16x2 acc[4];
    f16x2 hz = {(_Float16)0.f, (_Float16)0.f};
#pragma unroll
    for (int k = 0; k < 4; ++k) acc[k] = hz;

    for (int e0 = beg; e0 < end; e0 += 64) {
        int cnt = min(end - e0, 64);
        unsigned sv = (lane < cnt) ? rec[e0 + lane] : sentin;
        int cntR = (cnt + 15) & ~15;
        for (int j = 0; j < cntR; j += 16) {
            unsigned o0 = (unsigned)__shfl((int)sv, j + qtr, 64) + laneoff;
            unsigned o1 = (unsigned)__shfl((int)sv, j + 4 + qtr, 64) + laneoff;
            unsigned o2 = (unsigned)__shfl((int)sv, j + 8 + qtr, 64) + laneoff;
            unsigned o3 = (unsigned)__shfl((int)sv, j + 12 + qtr, 64) + laneoff;
            uint4 u0 = *(const uint4*)(Hb8 + o0);
            uint4 u1 = *(const uint4*)(Hb8 + o1);
            uint4 u2 = *(const uint4*)(Hb8 + o2);
            uint4 u3 = *(const uint4*)(Hb8 + o3);
            acc[0] += as_h2(u0.x);
            acc[1] += as_h2(u0.y);
            acc[2] += as_h2(u0.z);
            acc[3] += as_h2(u0.w);
            acc[0] += as_h2(u1.x);
            acc[1] += as_h2(u1.y);
            acc[2] += as_h2(u1.z);
            acc[3] += as_h2(u1.w);
            acc[0] += as_h2(u2.x);
            acc[1] += as_h2(u2.y);
            acc[2] += as_h2(u2.z);
            acc[3] += as_h2(u2.w);
            acc[0] += as_h2(u3.x);
            acc[1] += as_h2(u3.y);
            acc[2] += as_h2(u3.z);
            acc[3] += as_h2(u3.w);
        }
    }

#pragma unroll
    for (int k = 0; k < 4; ++k) {
        acc[k] += as_h2(__shfl_xor(as_u(acc[k]), 16, 64));
        acc[k] += as_h2(__shfl_xor(as_u(acc[k]), 32, 64));
    }

    unsigned mu = as_u(acc[0]);
    mu = (qtr == 1) ? as_u(acc[1]) : mu;
    mu = (qtr == 2) ? as_u(acc[2]) : mu;
    mu = (qtr == 3) ? as_u(acc[3]) : mu;
    f16x2 mine = as_h2(mu);
    const int c0 = sub * 8 + qtr * 2;
    const unsigned nodeoff = ((unsigned)node << 8) + (unsigned)c0 * 2;

    float dv = dinv[node];
    f16x2 hh = as_h2(*(const unsigned*)(Hb8 + nodeoff));   // h'[node] (pre-scaled)
    float2 bb = *(const float2*)(bias + c0);
    float a0 = ((float)mine.x + (float)hh.x) * dv + bb.x;
    float a1 = ((float)mine.y + (float)hh.y) * dv + bb.y;

    float s1 = a0 + a1;
    float s2 = a0 * a0 + a1 * a1;
#pragma unroll
    for (int mk = 1; mk <= 32; mk <<= 1) {
        s1 += __shfl_xor(s1, mk, 64);
        s2 += __shfl_xor(s2, mk, 64);
    }
    float mean = s1 * (1.0f / 128.0f);
    float var  = s2 * (1.0f / 128.0f) - mean * mean;
    float rr   = rsqrtf(var + 1e-5f);
    float2 gg = *(const float2*)(g + c0);
    float2 ee = *(const float2*)(be + c0);
    float r0 = (a0 - mean) * rr * gg.x + ee.x;
    float r1 = (a1 - mean) * rr * gg.y + ee.y;
    r0 = r0 > 0.0f ? r0 : expm1f(r0);
    r1 = r1 > 0.0f ? r1 : expm1f(r1);
    if (xin) {
        f16x2 xi = as_h2(*(const unsigned*)((const char*)xin + nodeoff));
        r0 += (float)xi.x;
        r1 += (float)xi.y;
    }
    *(unsigned*)((char*)outb + nodeoff) = pack_h2(r0, r1);
}

// ---------------------------------------------------------------- MFMA classifier, f16 input: 32 rows/wave, Wc via LDS
__global__ __launch_bounds__(256) void classifier_mfma(const unsigned short* __restrict__ Xh,
                                                       const unsigned short* __restrict__ Wcsw,
                                                       const float* __restrict__ bc,
                                                       float* __restrict__ out) {
    __shared__ unsigned short wlds[12 * 512];   // 12 KB
    const int tid   = threadIdx.x;
    const int lane  = tid & 63;
    const int wave  = tid >> 6;
    const int row0w = blockIdx.x * 128 + wave * 32;
    const int m = lane & 15;
    const int q = lane >> 4;

    {
        const uint4* srcp = (const uint4*)Wcsw;
        uint4*       dstp = (uint4*)wlds;
#pragma unroll
        for (int i = 0; i < 3; ++i) dstp[tid + i * 256] = srcp[tid + i * 256];
    }
    __syncthreads();

    f16x8 wf[12];
#pragma unroll
    for (int f = 0; f < 12; ++f)
        wf[f] = *(const f16x8*)(wlds + (f << 9) + lane * 8);

    f16x8 af[2][4];
#pragma unroll
    for (int ggr = 0; ggr < 2; ++ggr) {
        int r = row0w + ggr * 16 + m;
        if (r >= N_NODES) r = N_NODES - 1;
        const unsigned short* xp = Xh + (size_t)r * DIM + q * 8;
#pragma unroll
        for (int s = 0; s < 4; ++s) af[ggr][s] = *(const f16x8*)(xp + s * 32);
    }

    f32x4 acc[2][3];
    f32x4 z = {0.f, 0.f, 0.f, 0.f};
#pragma unroll
    for (int ggr = 0; ggr < 2; ++ggr)
#pragma unroll
        for (int n = 0; n < 3; ++n) acc[ggr][n] = z;

#pragma unroll
    for (int s = 0; s < 4; ++s)
#pragma unroll
        for (int n = 0; n < 3; ++n) {
            acc[0][n] = __builtin_amdgcn_mfma_f32_16x16x32_f16(af[0][s], wf[n * 4 + s], acc[0][n], 0, 0, 0);
            acc[1][n] = __builtin_amdgcn_mfma_f32_16x16x32_f16(af[1][s], wf[n * 4 + s], acc[1][n], 0, 0, 0);
        }

    float bcv[3];
#pragma unroll
    for (int n = 0; n < 3; ++n) {
        int c = 3 * m + n;
        bcv[n] = (c < NCLS) ? bc[c] : 0.f;
    }

#pragma unroll
    for (int ggr = 0; ggr < 2; ++ggr)
#pragma unroll
        for (int j = 0; j < 4; ++j) {
            int row = row0w + ggr * 16 + q * 4 + j;
            if (row < N_NODES) {
#pragma unroll
                for (int n = 0; n < 3; ++n) {
                    int c = 3 * m + n;
                    if (c < NCLS)
                        out[(size_t)row * NCLS + c] = acc[ggr][n][j] + bcv[n];
                }
            }
        }
}

// ---------------------------------------------------------------- launch
extern "C" void kernel_launch(void* const* d_in, const int* in_sizes, int n_in,
                              void* d_out, int out_size, void* d_ws, size_t ws_size,
                              hipStream_t stream) {
    const float* x  = (const float*)d_in[0];
    const int*   ei = (const int*)d_in[1];
    const float* W[3]  = {(const float*)d_in[2], (const float*)d_in[6], (const float*)d_in[10]};
    const float* b[3]  = {(const float*)d_in[3], (const float*)d_in[7], (const float*)d_in[11]};
    const float* g[3]  = {(const float*)d_in[4], (const float*)d_in[8], (const float*)d_in[12]};
    const float* be[3] = {(const float*)d_in[5], (const float*)d_in[9], (const float*)d_in[13]};
    const float* Wc = (const float*)d_in[14];
    const float* bc = (const float*)d_in[15];
    float* out = (float*)d_out;

    char* ws = (char*)d_ws;
    const size_t NP = 400128;  // padded (N+1)*4 bytes
    float* dinv   = (float*)(ws);
    int*   rowptr = (int*)  (ws + NP);
    int*   bcnt   = (int*)  (ws + 2 * NP);
    int*   bbase  = (int*)  (ws + 2 * NP + 1024);
    int*   bcur   = (int*)  (ws + 2 * NP + 2048);
    unsigned* rec = (unsigned*)(ws + 2 * NP + 4096);
    unsigned short* Hh = (unsigned short*)(ws + 2 * NP + 4096 + (size_t)N_EDGES * 8);
    unsigned short* Ah = Hh + (size_t)(N_NODES + 64) * DIM;   // Hh has zero-pad rows
    unsigned short* Ch = Ah + (size_t)N_NODES * DIM;
    unsigned short* Wsw0 = Ch + (size_t)N_NODES * DIM;
    unsigned short* Wsw1 = Wsw0 + DIM * DIM;
    unsigned short* Wsw2 = Wsw1 + DIM * DIM;
    unsigned short* Wcsw = Wsw2 + DIM * DIM;   // 12*512 shorts
    unsigned* tmp = (unsigned*)Ch;             // aliases Ch; dead before layer 0 writes Ch

    // ---- setup: zero bcnt (memset) + swizzles + bucket histogram (1 dispatch) ----
    hipMemsetAsync(bcnt, 0, 1024, stream);
    setup_misc<<<216 + P1_GRID, 256, 0, stream>>>(W[0], W[1], W[2], Wc, ei,
                                                  Wsw0, Wsw1, Wsw2, Wcsw, bcnt);

    // ---- CSR build (bucketed, packed tmp, fused phase 2) ----
    bscan<<<1, 256, 0, stream>>>(bcnt, bbase, bcur);
    bucket_p1<<<P1_GRID, 256, 0, stream>>>(ei, bcur, tmp);
    bucket_p2<<<NBUCK, 256, 0, stream>>>(tmp, bbase, rowptr, dinv, rec);

    const int gemm_grid = (N_NODES + 63) / 64;    // 1563 (covers pad rows to 100032)
    const int cls_grid  = (N_NODES + 127) / 128;  // 782
    const int agg_grid  = N_NODES / 4;            // 25000

    // layer 0: x fp32 -> Hh (scaled); agg -> Ch
    gemm_mfma_f<<<gemm_grid, 256, 0, stream>>>(x, Wsw0, dinv, Hh);
    agg_ln<<<agg_grid, 256, 0, stream>>>(Hh, nullptr, dinv, b[0], g[0], be[0], rowptr, rec, Ch);

    // layer 1: Ch -> Hh (scaled); agg (+resid Ch) -> Ah
    gemm_mfma_h<<<gemm_grid, 256, 0, stream>>>(Ch, Wsw1, dinv, Hh);
    agg_ln<<<agg_grid, 256, 0, stream>>>(Hh, Ch, dinv, b[1], g[1], be[1], rowptr, rec, Ah);

    // layer 2: Ah -> Hh (scaled); agg (+resid Ah) -> Ch
    gemm_mfma_h<<<gemm_grid, 256, 0, stream>>>(Ah, Wsw2, dinv, Hh);
    agg_ln<<<agg_grid, 256, 0, stream>>>(Hh, Ah, dinv, b[2], g[2], be[2], rowptr, rec, Ch);

    classifier_mfma<<<cls_grid, 256, 0, stream>>>(Ch, Wcsw, bc, out);
}